// Round 1
// baseline (5424.242 us; speedup 1.0000x reference)
//
#include <hip/hip_runtime.h>
#include <hip/hip_cooperative_groups.h>

namespace cg = cooperative_groups;

#define N_      800
#define C_      64
#define TRS_    40
#define SPT_    10
#define T_      400
#define HIST_   520           // 120 history slots + 400 produced slots (time-major)
#define KPL     13            // edges per lane: 13*64 = 832 >= 800
#define SENT    0x7FC00BADu   // qNaN sentinel for "not yet written"

#define A_F     (-0.5f)
#define OMEGA_F (10.0f)
#define G_F     (500.0f)
#define KGI_F   (5.0f)
#define DT_F    (1e-4f)

#define ALD(p)    __hip_atomic_load((p), __ATOMIC_RELAXED, __HIP_MEMORY_SCOPE_AGENT)
#define AST(p,v)  __hip_atomic_store((p), (v), __ATOMIC_RELAXED, __HIP_MEMORY_SCOPE_AGENT)

// ---------------- prelude kernels (unchanged, proven) ----------------

__global__ void k_sumsq(const float* __restrict__ sc, float* __restrict__ sumsq) {
    __shared__ float sh[4];
    int tid = threadIdx.x;
    int idx = blockIdx.x * 256 + tid;
    float s = 0.f;
    for (int i = idx; i < N_ * N_; i += 256 * 256) { float v = sc[i]; s += v * v; }
    #pragma unroll
    for (int o = 1; o < 64; o <<= 1) s += __shfl_xor(s, o, 64);
    if ((tid & 63) == 0) sh[tid >> 6] = s;
    __syncthreads();
    if (tid == 0) atomicAdd(sumsq, sh[0] + sh[1] + sh[2] + sh[3]);
}

__global__ void k_detect(const int* __restrict__ dw, int* __restrict__ flag) {
    __shared__ int sh[4];
    int tid = threadIdx.x;
    int v = 0;
    for (int idx = 2 * tid + 1; idx < 800; idx += 512) v |= dw[idx];
    #pragma unroll
    for (int o = 1; o < 64; o <<= 1) v |= __shfl_xor(v, o, 64);
    if ((tid & 63) == 0) sh[tid >> 6] = v;
    __syncthreads();
    if (tid == 0) flag[0] = ((sh[0] | sh[1] | sh[2] | sh[3]) == 0) ? 1 : 0; // 1 => int64
}

// time-major state array: xg[s*800 + j] = x_j(s-120); s in [0,120) from hE, rest SENT
__global__ void k_init(const float* __restrict__ hE, unsigned int* __restrict__ xg) {
    int idx = blockIdx.x * 256 + threadIdx.x;
    if (idx >= HIST_ * N_) return;
    int s = idx / N_, j = idx - s * N_;
    unsigned int v = (s < 120) ? __float_as_uint(hE[j * 120 + (119 - s)]) : SENT;
    xg[idx] = v;
}

// ---------------- main persistent kernel ----------------
// 100 blocks x 512 threads = 800 waves; wave (block b, wave w) owns row i = b*8+w.
// Per step: read LEd from own LDS ring slot, integrate, publish x to time-major xg,
// cooperatively poll the full 800-vector (each wave a 100-col chunk) into LDS,
// barrier, then scatter w[k]*x_j into ring slots (t+1+d[k]) & 127.

__global__ void __launch_bounds__(512, 1) k_main(
    const float* __restrict__ sc, const int* __restrict__ dw,
    const float* __restrict__ hx, const float* __restrict__ external,
    const float* __restrict__ noise, const float* __restrict__ lm,
    const float* __restrict__ sumsq, const int* __restrict__ flag,
    unsigned int* __restrict__ xg, float* __restrict__ xtr, float* __restrict__ out)
{
    cg::grid_group grid = cg::this_grid();
    __shared__ float xsh[2][N_];      // double-buffered copy of X[t][0..800)
    __shared__ float ring[8][128];    // per-row delay ring (slot period 128 > max span 120)

    const int lane = threadIdx.x & 63;
    const int wid  = threadIdx.x >> 6;        // 0..7
    const int i    = blockIdx.x * 8 + wid;    // row 0..799
    const int B0   = blockIdx.x * 8;

    const float inv_norm = 1.0f / sqrtf(*sumsq);
    const int is64 = *flag;

    // per-lane edge metadata: j = k*64+lane
    float w[KPL]; int dl[KPL];
    float rsum = 0.f;
    #pragma unroll
    for (int k = 0; k < KPL; ++k) {
        int j = k * 64 + lane;
        bool valid = (j < N_);
        int jj = valid ? j : 0;
        int base = i * N_ + jj;
        float wv = valid ? fabsf(sc[base]) * inv_norm : 0.f;
        dl[k] = valid ? dw[is64 ? (base << 1) : base] : 0;
        w[k]  = wv;
        rsum += wv;
    }
    #pragma unroll
    for (int o = 1; o < 64; o <<= 1) rsum += __shfl_xor(rsum, o, 64);

    // zero own ring (only this wave ever touches ring[wid])
    ring[wid][lane] = 0.f;
    ring[wid][64 + lane] = 0.f;

    float x = hx[2 * i], y = hx[2 * i + 1];

    // ---- prologue: scatter initial history s = -120..-1 (slots 0..119, cached reads) ----
    #pragma unroll 1
    for (int s = 0; s < 120; ++s) {
        #pragma unroll
        for (int k = 0; k < KPL; ++k) {
            if (w[k] != 0.f) {
                float v = __uint_as_float(xg[s * N_ + k * 64 + lane]);
                int tt = s - 119 + dl[k];        // (s-120) + 1 + d  -> target time
                if (tt >= 0) atomicAdd(&ring[wid][tt & 127], w[k] * v);
            }
        }
    }

    // ---- main loop ----
    #pragma unroll 1
    for (int t = 0; t < T_; ++t) {
        // 1. coupling term: complete (scatter for s=t-1 done last iteration, same wave)
        float led = ring[wid][t & 127];
        if (lane == 0) ring[wid][t & 127] = 0.f;   // reused for time t+128 (earliest add: s=t+8)

        // 2. integrate (replicated across lanes), publish
        int tr = (t * 205) >> 11;                  // t/10 for t<400
        int sp = t - tr * 10;
        float u  = external[(i * SPT_ + sp) * TRS_ + tr];
        float n0 = noise[(t * N_ + i) * 2 + 0];
        float n1 = noise[(t * N_ + i) * 2 + 1];

        float r2 = x * x + y * y;
        float dx = (A_F - r2) * x - OMEGA_F * y + G_F * (led - rsum * x) + KGI_F * u;
        float dy = (A_F - r2) * y + OMEGA_F * x;
        x = x + DT_F * dx + n0;
        y = y + DT_F * dy + n1;

        int par = t & 1;
        unsigned int* Xrow = xg + (120 + t) * N_;
        if (lane == 0) {
            AST(&Xrow[i], __float_as_uint(x));     // global publish (other blocks)
            xsh[par][i] = x;                       // local publish (own block)
            if (sp == SPT_ - 1) xtr[tr * N_ + i] = x;
        }

        // 3. cooperative poll: this wave owns columns [wid*100, wid*100+100),
        //    own-block rows are excluded (delivered via xsh by their owners)
        int j0 = wid * 100 + lane;
        int j1 = j0 + 64;
        bool m0 = !(j0 >= B0 && j0 < B0 + 8);
        bool m1 = (lane < 36) && !(j1 >= B0 && j1 < B0 + 8);
        unsigned int v0 = m0 ? ALD(&Xrow[j0]) : 0u;
        unsigned int v1 = m1 ? ALD(&Xrow[j1]) : 0u;
        int g = 0;
        while (__any((v0 == SENT) || (v1 == SENT))) {
            if (++g > 1000000) break;              // safety valve (never expected)
            if (v0 == SENT) v0 = ALD(&Xrow[j0]);
            if (v1 == SENT) v1 = ALD(&Xrow[j1]);
        }
        if (m0) xsh[par][j0] = __uint_as_float(v0);
        if (m1) xsh[par][j1] = __uint_as_float(v1);
        __syncthreads();

        // 4. scatter s=t forward into ring slots (t+1+d) & 127
        #pragma unroll
        for (int k = 0; k < KPL; ++k) {
            if (w[k] != 0.f) {
                float v = xsh[par][k * 64 + lane];
                atomicAdd(&ring[wid][(t + 1 + dl[k]) & 127], w[k] * v);
            }
        }
    }

    grid.sync();   // make xtr visible for the epilogue

    // epilogue: out[c*TRS + tr] = 5 * dot(xtr[tr,:], lm[c,:]) - 2
    for (int o = i; o < C_ * TRS_; o += 800) {
        int c = o / TRS_, tr = o - c * TRS_;
        float s = 0.f;
        #pragma unroll
        for (int k = 0; k < KPL; ++k) {
            int n = k * 64 + lane;
            if (n < N_) s += xtr[tr * N_ + n] * lm[c * N_ + n];
        }
        #pragma unroll
        for (int o2 = 1; o2 < 64; o2 <<= 1) s += __shfl_xor(s, o2, 64);
        if (lane == 0) out[o] = 5.0f * s - 2.0f;
    }
}

// ---------------- launch ----------------

extern "C" void kernel_launch(void* const* d_in, const int* in_sizes, int n_in,
                              void* d_out, int out_size, void* d_ws, size_t ws_size,
                              hipStream_t stream) {
    const float* external = (const float*)d_in[0];
    const float* hx       = (const float*)d_in[1];
    const float* hE       = (const float*)d_in[2];
    const float* sc       = (const float*)d_in[3];
    const float* lm       = (const float*)d_in[4];
    const float* noise    = (const float*)d_in[5];
    const int*   delays   = (const int*)  d_in[6];
    float* out = (float*)d_out;

    float*        sumsq = (float*)d_ws;                    // ws[0]
    int*          flag  = (int*)d_ws + 1;                  // ws[1]
    unsigned int* xg    = (unsigned int*)d_ws + 64;        // 520*800 words, time-major
    float*        xtr   = (float*)(xg + HIST_ * N_);       // 40*800 floats

    hipMemsetAsync(d_ws, 0, 8, stream);
    k_sumsq<<<256, 256, 0, stream>>>(sc, sumsq);
    k_detect<<<1, 256, 0, stream>>>(delays, flag);
    k_init<<<(HIST_ * N_ + 255) / 256, 256, 0, stream>>>(hE, xg);

    void* args[] = { (void*)&sc, (void*)&delays, (void*)&hx, (void*)&external,
                     (void*)&noise, (void*)&lm, (void*)&sumsq, (void*)&flag,
                     (void*)&xg, (void*)&xtr, (void*)&out };
    hipLaunchCooperativeKernel((const void*)k_main, dim3(100), dim3(512), args, 0, stream);
}

// Round 2
// 4277.075 us; speedup vs baseline: 1.2682x; 1.2682x over previous
//
#include <hip/hip_runtime.h>
#include <hip/hip_cooperative_groups.h>

namespace cg = cooperative_groups;

#define N_      800
#define C_      64
#define TRS_    40
#define SPT_    10
#define T_      400
#define HIST_   520           // 120 history + 400 produced rows (time-major)
#define KPL     13            // edges per lane: 13*64 = 832 >= 800
#define SENT    0x7FC00BADu   // qNaN sentinel for "not yet written"

#define A_F     (-0.5f)
#define OMEGA_F (10.0f)
#define G_F     (500.0f)
#define KGI_F   (5.0f)
#define DT_F    (1e-4f)

#define ALD(p)    __hip_atomic_load((p), __ATOMIC_RELAXED, __HIP_MEMORY_SCOPE_AGENT)
#define AST(p,v)  __hip_atomic_store((p), (v), __ATOMIC_RELAXED, __HIP_MEMORY_SCOPE_AGENT)

// ---------------- prelude kernels (unchanged, proven) ----------------

__global__ void k_sumsq(const float* __restrict__ sc, float* __restrict__ sumsq) {
    __shared__ float sh[4];
    int tid = threadIdx.x;
    int idx = blockIdx.x * 256 + tid;
    float s = 0.f;
    for (int i = idx; i < N_ * N_; i += 256 * 256) { float v = sc[i]; s += v * v; }
    #pragma unroll
    for (int o = 1; o < 64; o <<= 1) s += __shfl_xor(s, o, 64);
    if ((tid & 63) == 0) sh[tid >> 6] = s;
    __syncthreads();
    if (tid == 0) atomicAdd(sumsq, sh[0] + sh[1] + sh[2] + sh[3]);
}

__global__ void k_detect(const int* __restrict__ dw, int* __restrict__ flag) {
    __shared__ int sh[4];
    int tid = threadIdx.x;
    int v = 0;
    for (int idx = 2 * tid + 1; idx < 800; idx += 512) v |= dw[idx];
    #pragma unroll
    for (int o = 1; o < 64; o <<= 1) v |= __shfl_xor(v, o, 64);
    if ((tid & 63) == 0) sh[tid >> 6] = v;
    __syncthreads();
    if (tid == 0) flag[0] = ((sh[0] | sh[1] | sh[2] | sh[3]) == 0) ? 1 : 0; // 1 => int64
}

// time-major state: xg[(120+time)*800 + j] = x_j(time); rows 0..119 from hE, rest SENT
__global__ void k_init(const float* __restrict__ hE, unsigned int* __restrict__ xg) {
    int idx = blockIdx.x * 256 + threadIdx.x;
    if (idx >= HIST_ * N_) return;
    int s = idx / N_, j = idx - s * N_;
    unsigned int v = (s < 120) ? __float_as_uint(hE[j * 120 + (119 - s)]) : SENT;
    xg[idx] = v;
}

// ---------------- main persistent kernel ----------------
// 100 blocks x 512 threads; wave (b,w) owns row i = b*8+w.
// Delay classes:  d<2   : per-wave scattered ALD poll (fresh, ~13 lanes active)
//                 2..17 : gather from rolling LDS window W (row t-3 staged each step,
//                         3 steps of slack hides store->LLC->load latency)
//                 >=18  : scatter-forward into per-row LDS ring, batched every 16
//                         steps, sourced from W (no global traffic at all)

__global__ void __launch_bounds__(512, 1) k_main(
    const float* __restrict__ sc, const int* __restrict__ dw,
    const float* __restrict__ hx, const float* __restrict__ external,
    const float* __restrict__ noise, const float* __restrict__ lm,
    const float* __restrict__ sumsq, const int* __restrict__ flag,
    unsigned int* __restrict__ xg, float* __restrict__ xtr, float* __restrict__ out)
{
    cg::grid_group grid = cg::this_grid();
    __shared__ float W[16 * N_];      // rolling window: row s at slot (s & 15)
    __shared__ float ring[8][128];    // per-row far-coupling ring (span <= 117 < 128)

    const int tid  = threadIdx.x;
    const int lane = tid & 63;
    const int wid  = tid >> 6;
    const int i    = blockIdx.x * 8 + wid;

    const float inv_norm = 1.0f / sqrtf(*sumsq);
    const int is64 = *flag;

    // per-lane edge metadata
    float w_[KPL]; int d_[KPL];
    float rsum = 0.f;
    #pragma unroll
    for (int k = 0; k < KPL; ++k) {
        int j = k * 64 + lane;
        bool valid = (j < N_);
        int jj = valid ? j : 0;
        int base = i * N_ + jj;
        float wv = valid ? fabsf(sc[base]) * inv_norm : 0.f;
        d_[k] = valid ? dw[is64 ? (base << 1) : base] : 0;
        w_[k] = wv;
        rsum += wv;
    }
    #pragma unroll
    for (int o = 1; o < 64; o <<= 1) rsum += __shfl_xor(rsum, o, 64);

    // zero own ring (wave-private: only wave wid touches ring[wid])
    ring[wid][lane] = 0.f;
    ring[wid][64 + lane] = 0.f;

    // ---- prologue A: far-history scatter, sources s in [-120, -19] ----
    // (sources [-18,-3] are covered by the t=0 batch from W; [-2,-1] by the t=16 batch)
    #pragma unroll 1
    for (int s = -120; s <= -19; ++s) {
        const unsigned int* row = xg + (120 + s) * N_;   // history rows, never SENT
        #pragma unroll
        for (int k = 0; k < KPL; ++k) {
            if (d_[k] >= 18 && w_[k] != 0.f) {
                int tt = s + 1 + d_[k];
                if (tt >= 0)
                    atomicAdd(&ring[wid][tt & 127], w_[k] * __uint_as_float(row[(k * 64 + lane < N_) ? k * 64 + lane : 0]));
            }
        }
    }

    // ---- prologue B: pre-stage W rows s = -19..-4 (xg rows 101..116) ----
    for (int r = 0; r < 16; ++r) {
        int slot = (r + 13) & 15;                       // (-19 + r) & 15
        for (int idx = tid; idx < N_; idx += 512)
            W[slot * N_ + idx] = __uint_as_float(xg[(101 + r) * N_ + idx]);
    }

    float x = hx[2 * i], y = hx[2 * i + 1];
    __syncthreads();

    #pragma unroll 1
    for (int t = 0; t < T_; ++t) {
        // ---- 1. stage global row (t-3) into W slot (t-3)&15 (3-step slack) ----
        {
            const int g0 = (117 + t) * N_;
            const int so = ((t + 13) & 15) * N_;
            for (int idx = tid; idx < N_; idx += 512) {
                unsigned int v = xg[g0 + idx];          // cached read first
                int g = 0;
                while (v == SENT) { v = ALD(&xg[g0 + idx]); if (++g > 100000000) break; }
                W[so + idx] = __uint_as_float(v);
            }
        }
        __syncthreads();

        // ---- 2. far batch scatter every 16 steps: sources [t-18, t-3] from W ----
        if ((t & 15) == 0) {
            #pragma unroll 1
            for (int r = 0; r < 16; ++r) {
                int s = t - 18 + r;
                const float* Wr = W + (s & 15) * N_;
                #pragma unroll
                for (int k = 0; k < KPL; ++k) {
                    if (d_[k] >= 18 && w_[k] != 0.f) {
                        int j = k * 64 + lane;
                        atomicAdd(&ring[wid][(s + 1 + d_[k]) & 127],
                                  w_[k] * Wr[(j < N_) ? j : 0]);
                    }
                }
            }
        }

        // ---- 3. gather: W-near (2<=d<=17) + direct poll (d<2) ----
        float acc = 0.f;
        #pragma unroll
        for (int k = 0; k < KPL; ++k) {
            int dv = d_[k];
            bool inW = (dv >= 2) & (dv <= 17);
            float wv = inW ? w_[k] : 0.f;
            int slot = (t + 31 - dv) & 15;              // (t-1-d) mod 16
            int j = k * 64 + lane;
            acc += wv * W[slot * N_ + ((j < N_) ? j : 0)];
        }

        unsigned int vv[KPL];
        #pragma unroll
        for (int k = 0; k < KPL; ++k) {
            bool act = (d_[k] < 2) && (w_[k] != 0.f);
            int j = k * 64 + lane;
            vv[k] = act ? ALD(&xg[(119 - d_[k] + t) * N_ + ((j < N_) ? j : 0)]) : 0u;
        }
        int g = 0;
        while (true) {
            int pend = 0;
            #pragma unroll
            for (int k = 0; k < KPL; ++k) pend |= (vv[k] == SENT) ? 1 : 0;
            if (!__any(pend)) break;
            if (++g > 100000000) break;                 // safety valve (never expected)
            #pragma unroll
            for (int k = 0; k < KPL; ++k) {
                int j = k * 64 + lane;
                if (vv[k] == SENT)
                    vv[k] = ALD(&xg[(119 - d_[k] + t) * N_ + ((j < N_) ? j : 0)]);
            }
        }
        #pragma unroll
        for (int k = 0; k < KPL; ++k) acc += ((d_[k] < 2) ? w_[k] : 0.f) * __uint_as_float(vv[k]);
        #pragma unroll
        for (int o = 1; o < 64; o <<= 1) acc += __shfl_xor(acc, o, 64);

        float led = acc + ring[wid][t & 127];           // ring value uniform across lanes
        if (lane == 0) ring[wid][t & 127] = 0.f;        // slot reused >= 11 steps later

        // ---- 4. integrate / publish ----
        int tr = (t * 205) >> 11;                       // t/10 for t<400
        int sp = t - tr * 10;
        float u  = external[(i * SPT_ + sp) * TRS_ + tr];
        float n0 = noise[(t * N_ + i) * 2 + 0];
        float n1 = noise[(t * N_ + i) * 2 + 1];

        float r2 = x * x + y * y;
        float dx = (A_F - r2) * x - OMEGA_F * y + G_F * (led - rsum * x) + KGI_F * u;
        float dy = (A_F - r2) * y + OMEGA_F * x;
        x = x + DT_F * dx + n0;
        y = y + DT_F * dy + n1;

        if (lane == 0) {
            AST(&xg[(120 + t) * N_ + i], __float_as_uint(x));
            if (sp == SPT_ - 1) xtr[tr * N_ + i] = x;
        }
        __syncthreads();    // protects W (next step overwrites slot (t-2)&15)
    }

    grid.sync();   // make xtr visible for the epilogue

    // epilogue: out[c*TRS + tr] = 5 * dot(xtr[tr,:], lm[c,:]) - 2
    for (int o = i; o < C_ * TRS_; o += 800) {
        int c = o / TRS_, tr = o - c * TRS_;
        float s = 0.f;
        #pragma unroll
        for (int k = 0; k < KPL; ++k) {
            int n = k * 64 + lane;
            if (n < N_) s += xtr[tr * N_ + n] * lm[c * N_ + n];
        }
        #pragma unroll
        for (int o2 = 1; o2 < 64; o2 <<= 1) s += __shfl_xor(s, o2, 64);
        if (lane == 0) out[o] = 5.0f * s - 2.0f;
    }
}

// ---------------- launch ----------------

extern "C" void kernel_launch(void* const* d_in, const int* in_sizes, int n_in,
                              void* d_out, int out_size, void* d_ws, size_t ws_size,
                              hipStream_t stream) {
    const float* external = (const float*)d_in[0];
    const float* hx       = (const float*)d_in[1];
    const float* hE       = (const float*)d_in[2];
    const float* sc       = (const float*)d_in[3];
    const float* lm       = (const float*)d_in[4];
    const float* noise    = (const float*)d_in[5];
    const int*   delays   = (const int*)  d_in[6];
    float* out = (float*)d_out;

    float*        sumsq = (float*)d_ws;                    // ws[0]
    int*          flag  = (int*)d_ws + 1;                  // ws[1]
    unsigned int* xg    = (unsigned int*)d_ws + 64;        // 520*800 words, time-major
    float*        xtr   = (float*)(xg + HIST_ * N_);       // 40*800 floats

    hipMemsetAsync(d_ws, 0, 8, stream);
    k_sumsq<<<256, 256, 0, stream>>>(sc, sumsq);
    k_detect<<<1, 256, 0, stream>>>(delays, flag);
    k_init<<<(HIST_ * N_ + 255) / 256, 256, 0, stream>>>(hE, xg);

    void* args[] = { (void*)&sc, (void*)&delays, (void*)&hx, (void*)&external,
                     (void*)&noise, (void*)&lm, (void*)&sumsq, (void*)&flag,
                     (void*)&xg, (void*)&xtr, (void*)&out };
    hipLaunchCooperativeKernel((const void*)k_main, dim3(100), dim3(512), args, 0, stream);
}